// Round 9
// baseline (155.668 us; speedup 1.0000x reference)
//
#include <hip/hip_runtime.h>

// ETNN layer, N=50000 cells, HID=64, DEG=16 neighbors, 4 nodes/cell, sp=3.
//
// Bilinear split of the per-pair message MLP:
//   x@W1 = f_i@W1[0:64] + f_j@W1[64:128] + geom*W1[128]
// -> aux    : positions passthrough + weight pre-swizzle (separate launch:
//             prep_pq reads w1pq; intra-launch block order is undefined)
// -> prep_pq: feat fp32->bf16 (featb) + centroids + P,Q = feat@[W1top|W1bot]
//             Q stored COLUMN-SPLIT: Q0 = cols 0..31, Q1 = cols 32..63
//             (3.2 MB each -> the random-gather working set fits per-XCD L2)
// -> gather : TWO PASSES (one per Q half), serialized on the stream so each
//             pass's random working set is L2-resident. One wave per 2 cells,
//             one column per lane; nbr/geom broadcast via readlane pairs.
// -> tail   : msg = s@W2+b2; hu = silu([feat|msg]@Wu1+bu1); out = feat+hu@Wu2+bu2
//
// MFMA layouts (HW-verified): A[m=lane&15][k=quad*8+j], B[k=quad*8+j][n=lane&15],
// D[row=quad*4+reg][col=lane&15]. Transposed stages put weights in A so D cols
// land 4-consecutive per lane (packed uint2 stores). Wave-private LDS
// round-trips ordered by __threadfence_block + may_alias types.

#define DEG 16

typedef __attribute__((ext_vector_type(8))) short short8;   // 8 bf16
typedef __attribute__((ext_vector_type(4))) float f32x4;    // MFMA acc
typedef uint2 uint2_a __attribute__((may_alias));
typedef uint4 uint4_a __attribute__((may_alias));

union HbRd { uint4_a u; short8 s; };
union Frag { short8 s; uint4 u; };

__device__ __forceinline__ unsigned f2bf(float f) {
  unsigned u = __float_as_uint(f);
  return (u + 0x7FFFu + ((u >> 16) & 1u)) >> 16;   // RNE fp32->bf16
}
__device__ __forceinline__ float bf2f(unsigned bits16) {
  return __uint_as_float(bits16 << 16);
}
__device__ __forceinline__ float silu(float h) {
  return h / (1.f + __expf(-h));
}

// ----------------------------------------------------------------- aux ----
// t<150000: positions copy (float4) | next 24576: weight pre-swizzle.
__global__ __launch_bounds__(256) void aux_kernel(
    const float* __restrict__ pos,
    const float* __restrict__ W1, const float* __restrict__ W2,
    const float* __restrict__ Wu1, const float* __restrict__ Wu2,
    float* __restrict__ outpos,
    unsigned short* __restrict__ w1pq, unsigned short* __restrict__ w2t,
    unsigned short* __restrict__ wu1t, unsigned short* __restrict__ wu2b)
{
  int t = blockIdx.x * 256 + threadIdx.x;
  if (t < 150000) {
    ((float4*)outpos)[t] = ((const float4*)pos)[t];
  } else if (t < 174576) {
    const int r = t - 150000;
    if (r < 8192) {
      // w1pq: A-frags of [W1top|W1bot]^T, [mt 0..7][kk 0..1]
      const int j = r & 7, l = (r >> 3) & 15, q = (r >> 7) & 3;
      const int f = r >> 9, kk = f & 1, mt = f >> 1;
      const int k = kk * 32 + q * 8 + j;        // feat dim 0..63
      const int m = mt * 16 + l;                // pq col 0..127
      w1pq[r] = (unsigned short)f2bf(
          (m < 64) ? W1[k * 64 + m] : W1[(k + 64) * 64 + (m - 64)]);
    } else if (r < 12288) {
      // w2t: A-frags of W2^T, [mt 0..3][kk 0..1]
      const int s = r - 8192;
      const int j = s & 7, l = (s >> 3) & 15, q = (s >> 7) & 3;
      const int f = s >> 9, kk = f & 1, mt = f >> 1;
      const int k = kk * 32 + q * 8 + j;
      w2t[s] = (unsigned short)f2bf(W2[k * 64 + mt * 16 + l]);
    } else if (r < 20480) {
      // wu1t: A-frags of Wu1^T, [mt 0..3][kk 0..3]
      const int s = r - 12288;
      const int j = s & 7, l = (s >> 3) & 15, q = (s >> 7) & 3;
      const int f = s >> 9, kk = f & 3, mt = f >> 2;
      const int k = kk * 32 + q * 8 + j;        // 0..127
      wu1t[s] = (unsigned short)f2bf(Wu1[k * 64 + mt * 16 + l]);
    } else {
      // wu2b: B-frags of Wu2, [nt 0..3][kk 0..1]
      const int s = r - 20480;
      const int j = s & 7, l = (s >> 3) & 15, q = (s >> 7) & 3;
      const int f = s >> 9, kk = f & 1, nt = f >> 1;
      const int k = kk * 32 + q * 8 + j;
      wu2b[s] = (unsigned short)f2bf(Wu2[k * 64 + nt * 16 + l]);
    }
  }
}

// ------------------------------------------------------------- prep_pq ----
// One wave per 16-cell tile: read feat fp32 (B-frag layout), convert to bf16
// (write featb + keep frags), centroids for own cells, then
// [P|Q]^T = Wpq^T x X^T ; packed uint2 stores into P / Q0 / Q1 buffers.
__global__ __launch_bounds__(256) void prep_pq_kernel(
    const float* __restrict__ feat, const float* __restrict__ pos,
    const unsigned short* __restrict__ w1pq,
    unsigned short* __restrict__ featb, float* __restrict__ cent4,
    unsigned short* __restrict__ Pb,
    unsigned short* __restrict__ Q0, unsigned short* __restrict__ Q1)
{
  const int lane = threadIdx.x & 63;
  const int wid  = threadIdx.x >> 6;
  const int quad = lane >> 4;
  const int l15  = lane & 15;

  const int tile = blockIdx.x * 4 + wid;
  const bool act = (tile < 3125);
  const int  tt  = act ? tile : 3124;
  const int  cr  = tt * 16 + l15;

  // feat rows -> bf16 frags (B-layout) + featb store
  short8 xf[2];
  #pragma unroll
  for (int kk = 0; kk < 2; ++kk) {
    const float4 f0 = *(const float4*)(feat + cr * 64 + kk * 32 + quad * 8);
    const float4 f1 = *(const float4*)(feat + cr * 64 + kk * 32 + quad * 8 + 4);
    Frag v;
    v.s[0] = (short)f2bf(f0.x); v.s[1] = (short)f2bf(f0.y);
    v.s[2] = (short)f2bf(f0.z); v.s[3] = (short)f2bf(f0.w);
    v.s[4] = (short)f2bf(f1.x); v.s[5] = (short)f2bf(f1.y);
    v.s[6] = (short)f2bf(f1.z); v.s[7] = (short)f2bf(f1.w);
    xf[kk] = v.s;
    if (act) *(uint4*)(featb + cr * 64 + kk * 32 + quad * 8) = v.u;
  }

  // centroid of own 4 nodes (lanes 0..15, one cell each)
  if (act && lane < 16) {
    const float4* pp = (const float4*)(pos + 12 * cr);
    const float4 a = pp[0], b = pp[1], c = pp[2];
    float4 o;
    o.x = (a.x + a.w + b.z + c.y) * 0.25f;
    o.y = (a.y + b.x + b.w + c.z) * 0.25f;
    o.z = (a.z + b.y + c.x + c.w) * 0.25f;
    o.w = 0.f;
    ((float4*)cent4)[cr] = o;
  }

  short8 wf[8][2];
  #pragma unroll
  for (int mt = 0; mt < 8; ++mt)
    #pragma unroll
    for (int kk = 0; kk < 2; ++kk)
      wf[mt][kk] = *(const short8*)(w1pq + (((mt * 2 + kk) * 4 + quad) << 7) + l15 * 8);

  f32x4 acc[8] = {};
  #pragma unroll
  for (int kk = 0; kk < 2; ++kk)
    #pragma unroll
    for (int mt = 0; mt < 8; ++mt)
      acc[mt] = __builtin_amdgcn_mfma_f32_16x16x32_bf16(wf[mt][kk], xf[kk], acc[mt], 0, 0, 0);

  if (act) {
    #pragma unroll
    for (int mt = 0; mt < 8; ++mt) {
      uint2 pk;
      pk.x = f2bf(acc[mt][0]) | (f2bf(acc[mt][1]) << 16);
      pk.y = f2bf(acc[mt][2]) | (f2bf(acc[mt][3]) << 16);
      unsigned short* dst;
      if (mt < 4)      dst = Pb + cr * 64 + mt * 16 + quad * 4;
      else if (mt < 6) dst = Q0 + cr * 32 + (mt - 4) * 16 + quad * 4;
      else             dst = Q1 + cr * 32 + (mt - 6) * 16 + quad * 4;
      *(uint2*)dst = pk;
    }
  }
}

// -------------------------------------------------------------- gather ----
// One wave per TWO cells; lane = sub*32 + col (col within the 32-col half).
// nbr ids + geom broadcast via readlane pairs (one per sub-cell) + select;
// Q-half rows are 64B coalesced segments. Launched twice (Q0 then Q1),
// serialized on the stream so each pass's 3.2MB working set is L2-resident.
__global__ __launch_bounds__(256) void gather_half_kernel(
    const unsigned short* __restrict__ Qh,   // [50000][32] bf16
    const unsigned short* __restrict__ Pb,
    const float4* __restrict__ cent4,
    const int* __restrict__ nbr,
    const float* __restrict__ b1, const float* __restrict__ W1,
    unsigned short* __restrict__ sB,
    int colofs)
{
  const int lane = threadIdx.x & 63;
  const int wid  = threadIdx.x >> 6;
  const int sub  = lane >> 5;            // which of the wave's 2 cells
  const int col  = lane & 31;            // column within the half
  const int c    = (blockIdx.x * 4 + wid) * 2 + sub;   // 6250 blocks

  // lanes (lane&31)<16 carry the sub-cell's 16 neighbor ids
  const int nj = nbr[c * DEG + (lane & 15)];

  const float4 ci = cent4[c];
  const float4 cj = cent4[nj];
  const float dx = ci.x - cj.x, dy = ci.y - cj.y, dz = ci.z - cj.z;
  const float g = sqrtf(dx * dx + dy * dy + dz * dz);

  const float pcb = bf2f(Pb[c * 64 + colofs + col]) + b1[colofs + col];
  const float wl  = W1[8192 + colofs + col];

  float acc = 0.f;
  #pragma unroll
  for (int d = 0; d < DEG; ++d) {
    const int   n0 = __builtin_amdgcn_readlane(nj, d);
    const int   n1 = __builtin_amdgcn_readlane(nj, 32 + d);
    const float g0 = __uint_as_float(
        __builtin_amdgcn_readlane((int)__float_as_uint(g), d));
    const float g1 = __uint_as_float(
        __builtin_amdgcn_readlane((int)__float_as_uint(g), 32 + d));
    const int   ndl = sub ? n1 : n0;
    const float gdl = sub ? g1 : g0;
    const float qv  = bf2f(Qh[ndl * 32 + col]);
    acc += silu(pcb + qv + gdl * wl);
  }

  sB[c * 64 + colofs + col] = (unsigned short)f2bf(acc * 0.0625f);
}

// ---------------------------------------------------------------- tail ----
// Per 16-cell tile: msg^T = W2^T x s^T (+b2) -> LDS; hu^T = Wu1^T x [feat|msg]^T
// (+bu1, silu) -> LDS; out = hu x Wu2 + bu2 + feat.
__global__ __launch_bounds__(256) void tail_kernel(
    const unsigned short* __restrict__ featb,
    const unsigned short* __restrict__ sB,
    const float* __restrict__ feat,
    const unsigned short* __restrict__ w2t,
    const unsigned short* __restrict__ wu1t,
    const unsigned short* __restrict__ wu2b,
    const float* __restrict__ b2, const float* __restrict__ bu1,
    const float* __restrict__ bu2,
    float* __restrict__ outf)
{
  __shared__ uint4 smem[4 * 288];   // per wave: Msg 16x144B + Hb 16x144B
  const int lane = threadIdx.x & 63;
  const int wid  = threadIdx.x >> 6;
  const int quad = lane >> 4;
  const int l15  = lane & 15;
  char* Msg = (char*)(smem + wid * 288);
  char* Hb  = Msg + 2304;

  short8 w2f[4][2];
  #pragma unroll
  for (int mt = 0; mt < 4; ++mt)
    #pragma unroll
    for (int kk = 0; kk < 2; ++kk)
      w2f[mt][kk] = *(const short8*)(w2t + (((mt * 2 + kk) * 4 + quad) << 7) + l15 * 8);
  short8 wu1f[4][4];
  #pragma unroll
  for (int mt = 0; mt < 4; ++mt)
    #pragma unroll
    for (int kk = 0; kk < 4; ++kk)
      wu1f[mt][kk] = *(const short8*)(wu1t + (((mt * 4 + kk) * 4 + quad) << 7) + l15 * 8);
  short8 wu2f[4][2];
  #pragma unroll
  for (int nt = 0; nt < 4; ++nt)
    #pragma unroll
    for (int kk = 0; kk < 2; ++kk)
      wu2f[nt][kk] = *(const short8*)(wu2b + (((nt * 2 + kk) * 4 + quad) << 7) + l15 * 8);

  f32x4 b2f[4], bu1f[4];
  #pragma unroll
  for (int mt = 0; mt < 4; ++mt) {
    b2f[mt]  = *(const f32x4*)(b2  + mt * 16 + quad * 4);
    bu1f[mt] = *(const f32x4*)(bu1 + mt * 16 + quad * 4);
  }
  float bu2v[4];
  #pragma unroll
  for (int nt = 0; nt < 4; ++nt) bu2v[nt] = bu2[nt * 16 + l15];

  const int tile = blockIdx.x * 4 + wid;
  const bool act = (tile < 3125);
  const int  tt  = act ? tile : 3124;
  const int  cr  = tt * 16 + l15;

  // stage 1: msg^T = W2^T x s^T (+b2)
  f32x4 accm[4] = {};
  #pragma unroll
  for (int kk = 0; kk < 2; ++kk) {
    const short8 bf = *(const short8*)(sB + cr * 64 + kk * 32 + quad * 8);
    #pragma unroll
    for (int mt = 0; mt < 4; ++mt)
      accm[mt] = __builtin_amdgcn_mfma_f32_16x16x32_bf16(w2f[mt][kk], bf, accm[mt], 0, 0, 0);
  }
  #pragma unroll
  for (int mt = 0; mt < 4; ++mt) {
    uint2 pk;
    pk.x = f2bf(accm[mt][0] + b2f[mt][0]) | (f2bf(accm[mt][1] + b2f[mt][1]) << 16);
    pk.y = f2bf(accm[mt][2] + b2f[mt][2]) | (f2bf(accm[mt][3] + b2f[mt][3]) << 16);
    *(uint2_a*)(Msg + l15 * 144 + mt * 32 + quad * 8) = pk;
  }
  __threadfence_block();

  // stage 2: hu^T = Wu1^T x U^T, U = [feat | msg]
  f32x4 accu[4] = {};
  #pragma unroll
  for (int kk = 0; kk < 4; ++kk) {
    short8 bf;
    if (kk < 2) {
      bf = *(const short8*)(featb + cr * 64 + kk * 32 + quad * 8);
    } else {
      HbRd t; t.u = *(const uint4_a*)(Msg + l15 * 144 + (kk - 2) * 64 + quad * 16);
      bf = t.s;
    }
    #pragma unroll
    for (int mt = 0; mt < 4; ++mt)
      accu[mt] = __builtin_amdgcn_mfma_f32_16x16x32_bf16(wu1f[mt][kk], bf, accu[mt], 0, 0, 0);
  }
  #pragma unroll
  for (int mt = 0; mt < 4; ++mt) {
    float sv[4];
    #pragma unroll
    for (int rg = 0; rg < 4; ++rg)
      sv[rg] = silu(accu[mt][rg] + bu1f[mt][rg]);
    uint2 pk;
    pk.x = f2bf(sv[0]) | (f2bf(sv[1]) << 16);
    pk.y = f2bf(sv[2]) | (f2bf(sv[3]) << 16);
    *(uint2_a*)(Hb + l15 * 144 + mt * 32 + quad * 8) = pk;
  }
  __threadfence_block();

  // stage 3: out = hu x Wu2 + bu2 + feat
  f32x4 acc2[4] = {};
  #pragma unroll
  for (int kk = 0; kk < 2; ++kk) {
    HbRd t; t.u = *(const uint4_a*)(Hb + l15 * 144 + kk * 64 + quad * 16);
    const short8 af = t.s;
    #pragma unroll
    for (int nt = 0; nt < 4; ++nt)
      acc2[nt] = __builtin_amdgcn_mfma_f32_16x16x32_bf16(af, wu2f[nt][kk], acc2[nt], 0, 0, 0);
  }
  if (act) {
    #pragma unroll
    for (int nt = 0; nt < 4; ++nt)
      #pragma unroll
      for (int rg = 0; rg < 4; ++rg) {
        const int row = tt * 16 + quad * 4 + rg;
        const int col = nt * 16 + l15;
        outf[row * 64 + col] = feat[row * 64 + col] + acc2[nt][rg] + bu2v[nt];
      }
  }
}

// -------------------------------------------------------------- launch ----
extern "C" void kernel_launch(void* const* d_in, const int* in_sizes, int n_in,
                              void* d_out, int out_size, void* d_ws, size_t ws_size,
                              hipStream_t stream)
{
  const float* feat = (const float*)d_in[0];
  const float* pos  = (const float*)d_in[1];
  const int*   nbr  = (const int*)d_in[2];
  const float* W1   = (const float*)d_in[3];
  const float* b1   = (const float*)d_in[4];
  const float* W2   = (const float*)d_in[5];
  const float* b2   = (const float*)d_in[6];
  const float* Wu1  = (const float*)d_in[7];
  const float* bu1  = (const float*)d_in[8];
  const float* Wu2  = (const float*)d_in[9];
  const float* bu2  = (const float*)d_in[10];
  float* out = (float*)d_out;

  // ws: featb 6.4M @0 | Pb 6.4M @6.4M | Q0 3.2M @12.8M | Q1 3.2M @16.0M
  //   | sB 6.4M @19.2M | cent4 0.8M @25.6M | swizzled weights @26.4M
  unsigned short* featb = (unsigned short*)d_ws;
  unsigned short* Pb    = (unsigned short*)((char*)d_ws + 6400000);
  unsigned short* Q0    = (unsigned short*)((char*)d_ws + 12800000);
  unsigned short* Q1    = (unsigned short*)((char*)d_ws + 16000000);
  unsigned short* sB    = (unsigned short*)((char*)d_ws + 19200000);
  float*          cent4 = (float*)((char*)d_ws + 25600000);
  unsigned short* w1pq  = (unsigned short*)((char*)d_ws + 26400000);
  unsigned short* w2t   = (unsigned short*)((char*)d_ws + 26416384);
  unsigned short* wu1t  = (unsigned short*)((char*)d_ws + 26424576);
  unsigned short* wu2b  = (unsigned short*)((char*)d_ws + 26440960);

  aux_kernel<<<682, 256, 0, stream>>>(pos, W1, W2, Wu1, Wu2, out + 3200000,
                                      w1pq, w2t, wu1t, wu2b);
  prep_pq_kernel<<<782, 256, 0, stream>>>(feat, pos, w1pq, featb, cent4,
                                          Pb, Q0, Q1);
  gather_half_kernel<<<6250, 256, 0, stream>>>(Q0, Pb, (const float4*)cent4,
                                               nbr, b1, W1, sB, 0);
  gather_half_kernel<<<6250, 256, 0, stream>>>(Q1, Pb, (const float4*)cent4,
                                               nbr, b1, W1, sB, 32);
  tail_kernel<<<782, 256, 0, stream>>>(featb, sB, feat, w2t, wu1t, wu2b,
                                       b2, bu1, bu2, out);
}

// Round 10
// 132.386 us; speedup vs baseline: 1.1759x; 1.1759x over previous
//
#include <hip/hip_runtime.h>

// ETNN layer, N=50000 cells, HID=64, DEG=16 neighbors, 4 nodes/cell, sp=3.
//
// Bilinear split of the per-pair message MLP:
//   x@W1 = f_i@W1[0:64] + f_j@W1[64:128] + geom*W1[128]
// -> aux    : positions passthrough + weight pre-swizzle (separate launch:
//             prep_pq reads w1pq; intra-launch block order is undefined)
// -> prep_pq: feat fp32->bf16 (featb) + centroids + P (bf16) and Q (FP8 E4M3,
//             64B rows = ONE L1 line per random touch — the gather is L1
//             miss-throughput bound at ~17cyc/line/CU; fp8 halves line count)
// -> gather : one wave per cell, one column per lane; nbr/geom broadcast via
//             readlane (uniform-base addressing); fast silu via v_rcp.
// -> tail   : msg = s@W2+b2; hu = silu([feat|msg]@Wu1+bu1); out = feat+hu@Wu2+bu2
//
// MFMA layouts (HW-verified): A[m=lane&15][k=quad*8+j], B[k=quad*8+j][n=lane&15],
// D[row=quad*4+reg][col=lane&15]. Transposed stages put weights in A so D cols
// land 4-consecutive per lane (packed stores). Wave-private LDS round-trips
// ordered by __threadfence_block + may_alias types.

#define DEG 16

typedef __attribute__((ext_vector_type(8))) short short8;   // 8 bf16
typedef __attribute__((ext_vector_type(4))) float f32x4;    // MFMA acc
typedef uint2 uint2_a __attribute__((may_alias));
typedef uint4 uint4_a __attribute__((may_alias));

union HbRd { uint4_a u; short8 s; };
union Frag { short8 s; uint4 u; };

__device__ __forceinline__ unsigned f2bf(float f) {
  unsigned u = __float_as_uint(f);
  return (u + 0x7FFFu + ((u >> 16) & 1u)) >> 16;   // RNE fp32->bf16
}
__device__ __forceinline__ float bf2f(unsigned bits16) {
  return __uint_as_float(bits16 << 16);
}
__device__ __forceinline__ float silu(float h) {
  return h / (1.f + __expf(-h));
}
__device__ __forceinline__ float silu_fast(float h) {
  return h * __builtin_amdgcn_rcpf(1.f + __expf(-h));
}

// ----------------------------------------------------------------- aux ----
// t<150000: positions copy (float4) | next 24576: weight pre-swizzle.
__global__ __launch_bounds__(256) void aux_kernel(
    const float* __restrict__ pos,
    const float* __restrict__ W1, const float* __restrict__ W2,
    const float* __restrict__ Wu1, const float* __restrict__ Wu2,
    float* __restrict__ outpos,
    unsigned short* __restrict__ w1pq, unsigned short* __restrict__ w2t,
    unsigned short* __restrict__ wu1t, unsigned short* __restrict__ wu2b)
{
  int t = blockIdx.x * 256 + threadIdx.x;
  if (t < 150000) {
    ((float4*)outpos)[t] = ((const float4*)pos)[t];
  } else if (t < 174576) {
    const int r = t - 150000;
    if (r < 8192) {
      // w1pq: A-frags of [W1top|W1bot]^T, [mt 0..7][kk 0..1]
      const int j = r & 7, l = (r >> 3) & 15, q = (r >> 7) & 3;
      const int f = r >> 9, kk = f & 1, mt = f >> 1;
      const int k = kk * 32 + q * 8 + j;        // feat dim 0..63
      const int m = mt * 16 + l;                // pq col 0..127
      w1pq[r] = (unsigned short)f2bf(
          (m < 64) ? W1[k * 64 + m] : W1[(k + 64) * 64 + (m - 64)]);
    } else if (r < 12288) {
      // w2t: A-frags of W2^T, [mt 0..3][kk 0..1]
      const int s = r - 8192;
      const int j = s & 7, l = (s >> 3) & 15, q = (s >> 7) & 3;
      const int f = s >> 9, kk = f & 1, mt = f >> 1;
      const int k = kk * 32 + q * 8 + j;
      w2t[s] = (unsigned short)f2bf(W2[k * 64 + mt * 16 + l]);
    } else if (r < 20480) {
      // wu1t: A-frags of Wu1^T, [mt 0..3][kk 0..3]
      const int s = r - 12288;
      const int j = s & 7, l = (s >> 3) & 15, q = (s >> 7) & 3;
      const int f = s >> 9, kk = f & 3, mt = f >> 2;
      const int k = kk * 32 + q * 8 + j;        // 0..127
      wu1t[s] = (unsigned short)f2bf(Wu1[k * 64 + mt * 16 + l]);
    } else {
      // wu2b: B-frags of Wu2, [nt 0..3][kk 0..1]
      const int s = r - 20480;
      const int j = s & 7, l = (s >> 3) & 15, q = (s >> 7) & 3;
      const int f = s >> 9, kk = f & 1, nt = f >> 1;
      const int k = kk * 32 + q * 8 + j;
      wu2b[s] = (unsigned short)f2bf(Wu2[k * 64 + nt * 16 + l]);
    }
  }
}

// ------------------------------------------------------------- prep_pq ----
// One wave per 16-cell tile: read feat fp32 (B-frag layout), convert to bf16
// (write featb + keep frags), centroids for own cells, then
// [P|Q]^T = Wpq^T x X^T ; P -> bf16 (uint2), Q -> fp8 e4m3 (uint, HW cvt).
__global__ __launch_bounds__(256) void prep_pq_kernel(
    const float* __restrict__ feat, const float* __restrict__ pos,
    const unsigned short* __restrict__ w1pq,
    unsigned short* __restrict__ featb, float* __restrict__ cent4,
    unsigned short* __restrict__ Pb, unsigned char* __restrict__ Q8)
{
  const int lane = threadIdx.x & 63;
  const int wid  = threadIdx.x >> 6;
  const int quad = lane >> 4;
  const int l15  = lane & 15;

  const int tile = blockIdx.x * 4 + wid;
  const bool act = (tile < 3125);
  const int  tt  = act ? tile : 3124;
  const int  cr  = tt * 16 + l15;

  // feat rows -> bf16 frags (B-layout) + featb store
  short8 xf[2];
  #pragma unroll
  for (int kk = 0; kk < 2; ++kk) {
    const float4 f0 = *(const float4*)(feat + cr * 64 + kk * 32 + quad * 8);
    const float4 f1 = *(const float4*)(feat + cr * 64 + kk * 32 + quad * 8 + 4);
    Frag v;
    v.s[0] = (short)f2bf(f0.x); v.s[1] = (short)f2bf(f0.y);
    v.s[2] = (short)f2bf(f0.z); v.s[3] = (short)f2bf(f0.w);
    v.s[4] = (short)f2bf(f1.x); v.s[5] = (short)f2bf(f1.y);
    v.s[6] = (short)f2bf(f1.z); v.s[7] = (short)f2bf(f1.w);
    xf[kk] = v.s;
    if (act) *(uint4*)(featb + cr * 64 + kk * 32 + quad * 8) = v.u;
  }

  // centroid of own 4 nodes (lanes 0..15, one cell each)
  if (act && lane < 16) {
    const float4* pp = (const float4*)(pos + 12 * cr);
    const float4 a = pp[0], b = pp[1], c = pp[2];
    float4 o;
    o.x = (a.x + a.w + b.z + c.y) * 0.25f;
    o.y = (a.y + b.x + b.w + c.z) * 0.25f;
    o.z = (a.z + b.y + c.x + c.w) * 0.25f;
    o.w = 0.f;
    ((float4*)cent4)[cr] = o;
  }

  short8 wf[8][2];
  #pragma unroll
  for (int mt = 0; mt < 8; ++mt)
    #pragma unroll
    for (int kk = 0; kk < 2; ++kk)
      wf[mt][kk] = *(const short8*)(w1pq + (((mt * 2 + kk) * 4 + quad) << 7) + l15 * 8);

  f32x4 acc[8] = {};
  #pragma unroll
  for (int kk = 0; kk < 2; ++kk)
    #pragma unroll
    for (int mt = 0; mt < 8; ++mt)
      acc[mt] = __builtin_amdgcn_mfma_f32_16x16x32_bf16(wf[mt][kk], xf[kk], acc[mt], 0, 0, 0);

  if (act) {
    #pragma unroll
    for (int mt = 0; mt < 4; ++mt) {       // P: bf16
      uint2 pk;
      pk.x = f2bf(acc[mt][0]) | (f2bf(acc[mt][1]) << 16);
      pk.y = f2bf(acc[mt][2]) | (f2bf(acc[mt][3]) << 16);
      *(uint2*)(Pb + cr * 64 + mt * 16 + quad * 4) = pk;
    }
    #pragma unroll
    for (int mt = 4; mt < 8; ++mt) {       // Q: fp8 e4m3 (HW cvt pair)
      int w = __builtin_amdgcn_cvt_pk_fp8_f32(acc[mt][0], acc[mt][1], 0, false);
      w = __builtin_amdgcn_cvt_pk_fp8_f32(acc[mt][2], acc[mt][3], w, true);
      *(unsigned int*)(Q8 + cr * 64 + (mt - 4) * 16 + quad * 4) = (unsigned)w;
    }
  }
}

// -------------------------------------------------------------- gather ----
// One wave per cell, one column per lane. nbr ids + geom are wave-uniform
// per d: broadcast via readlane -> scalar-based coalesced 64B fp8 row loads
// (ONE L1 line per touch), in-lane mean accumulation, fast silu.
__global__ __launch_bounds__(256) void gather_kernel(
    const unsigned short* __restrict__ Pb,
    const unsigned char* __restrict__ Q8,
    const float4* __restrict__ cent4,
    const int* __restrict__ nbr,
    const float* __restrict__ b1, const float* __restrict__ W1,
    unsigned short* __restrict__ sB)
{
  const int lane = threadIdx.x & 63;
  const int wid  = threadIdx.x >> 6;
  const int c    = blockIdx.x * 4 + wid;   // 12500 blocks x 4 waves = 50000

  // lanes 0..15 carry the 16 neighbor ids (replicated x4 across the wave)
  const int nj = nbr[c * DEG + (lane & 15)];

  const float4 ci = cent4[c];
  const float4 cj = cent4[nj];
  const float dx = ci.x - cj.x, dy = ci.y - cj.y, dz = ci.z - cj.z;
  const float g = sqrtf(dx * dx + dy * dy + dz * dz);

  // per-column constants (lane = column)
  const float pcb = bf2f(Pb[c * 64 + lane]) + b1[lane];
  const float wl  = W1[8192 + lane];

  float acc = 0.f;
  #pragma unroll
  for (int d = 0; d < DEG; ++d) {
    const int   nd = __builtin_amdgcn_readlane(nj, d);
    const float gd = __uint_as_float(
        __builtin_amdgcn_readlane((int)__float_as_uint(g), d));
    const float qv = __builtin_amdgcn_cvt_f32_fp8((int)Q8[nd * 64 + lane], 0);
    acc += silu_fast(pcb + qv + gd * wl);
  }

  sB[c * 64 + lane] = (unsigned short)f2bf(acc * 0.0625f);
}

// ---------------------------------------------------------------- tail ----
// Per 16-cell tile: msg^T = W2^T x s^T (+b2) -> LDS; hu^T = Wu1^T x [feat|msg]^T
// (+bu1, silu) -> LDS; out = hu x Wu2 + bu2 + feat.
__global__ __launch_bounds__(256) void tail_kernel(
    const unsigned short* __restrict__ featb,
    const unsigned short* __restrict__ sB,
    const float* __restrict__ feat,
    const unsigned short* __restrict__ w2t,
    const unsigned short* __restrict__ wu1t,
    const unsigned short* __restrict__ wu2b,
    const float* __restrict__ b2, const float* __restrict__ bu1,
    const float* __restrict__ bu2,
    float* __restrict__ outf)
{
  __shared__ uint4 smem[4 * 288];   // per wave: Msg 16x144B + Hb 16x144B
  const int lane = threadIdx.x & 63;
  const int wid  = threadIdx.x >> 6;
  const int quad = lane >> 4;
  const int l15  = lane & 15;
  char* Msg = (char*)(smem + wid * 288);
  char* Hb  = Msg + 2304;

  short8 w2f[4][2];
  #pragma unroll
  for (int mt = 0; mt < 4; ++mt)
    #pragma unroll
    for (int kk = 0; kk < 2; ++kk)
      w2f[mt][kk] = *(const short8*)(w2t + (((mt * 2 + kk) * 4 + quad) << 7) + l15 * 8);
  short8 wu1f[4][4];
  #pragma unroll
  for (int mt = 0; mt < 4; ++mt)
    #pragma unroll
    for (int kk = 0; kk < 4; ++kk)
      wu1f[mt][kk] = *(const short8*)(wu1t + (((mt * 4 + kk) * 4 + quad) << 7) + l15 * 8);
  short8 wu2f[4][2];
  #pragma unroll
  for (int nt = 0; nt < 4; ++nt)
    #pragma unroll
    for (int kk = 0; kk < 2; ++kk)
      wu2f[nt][kk] = *(const short8*)(wu2b + (((nt * 2 + kk) * 4 + quad) << 7) + l15 * 8);

  f32x4 b2f[4], bu1f[4];
  #pragma unroll
  for (int mt = 0; mt < 4; ++mt) {
    b2f[mt]  = *(const f32x4*)(b2  + mt * 16 + quad * 4);
    bu1f[mt] = *(const f32x4*)(bu1 + mt * 16 + quad * 4);
  }
  float bu2v[4];
  #pragma unroll
  for (int nt = 0; nt < 4; ++nt) bu2v[nt] = bu2[nt * 16 + l15];

  const int tile = blockIdx.x * 4 + wid;
  const bool act = (tile < 3125);
  const int  tt  = act ? tile : 3124;
  const int  cr  = tt * 16 + l15;

  // stage 1: msg^T = W2^T x s^T (+b2)
  f32x4 accm[4] = {};
  #pragma unroll
  for (int kk = 0; kk < 2; ++kk) {
    const short8 bf = *(const short8*)(sB + cr * 64 + kk * 32 + quad * 8);
    #pragma unroll
    for (int mt = 0; mt < 4; ++mt)
      accm[mt] = __builtin_amdgcn_mfma_f32_16x16x32_bf16(w2f[mt][kk], bf, accm[mt], 0, 0, 0);
  }
  #pragma unroll
  for (int mt = 0; mt < 4; ++mt) {
    uint2 pk;
    pk.x = f2bf(accm[mt][0] + b2f[mt][0]) | (f2bf(accm[mt][1] + b2f[mt][1]) << 16);
    pk.y = f2bf(accm[mt][2] + b2f[mt][2]) | (f2bf(accm[mt][3] + b2f[mt][3]) << 16);
    *(uint2_a*)(Msg + l15 * 144 + mt * 32 + quad * 8) = pk;
  }
  __threadfence_block();

  // stage 2: hu^T = Wu1^T x U^T, U = [feat | msg]
  f32x4 accu[4] = {};
  #pragma unroll
  for (int kk = 0; kk < 4; ++kk) {
    short8 bf;
    if (kk < 2) {
      bf = *(const short8*)(featb + cr * 64 + kk * 32 + quad * 8);
    } else {
      HbRd t; t.u = *(const uint4_a*)(Msg + l15 * 144 + (kk - 2) * 64 + quad * 16);
      bf = t.s;
    }
    #pragma unroll
    for (int mt = 0; mt < 4; ++mt)
      accu[mt] = __builtin_amdgcn_mfma_f32_16x16x32_bf16(wu1f[mt][kk], bf, accu[mt], 0, 0, 0);
  }
  #pragma unroll
  for (int mt = 0; mt < 4; ++mt) {
    float sv[4];
    #pragma unroll
    for (int rg = 0; rg < 4; ++rg)
      sv[rg] = silu(accu[mt][rg] + bu1f[mt][rg]);
    uint2 pk;
    pk.x = f2bf(sv[0]) | (f2bf(sv[1]) << 16);
    pk.y = f2bf(sv[2]) | (f2bf(sv[3]) << 16);
    *(uint2_a*)(Hb + l15 * 144 + mt * 32 + quad * 8) = pk;
  }
  __threadfence_block();

  // stage 3: out = hu x Wu2 + bu2 + feat
  f32x4 acc2[4] = {};
  #pragma unroll
  for (int kk = 0; kk < 2; ++kk) {
    HbRd t; t.u = *(const uint4_a*)(Hb + l15 * 144 + kk * 64 + quad * 16);
    const short8 af = t.s;
    #pragma unroll
    for (int nt = 0; nt < 4; ++nt)
      acc2[nt] = __builtin_amdgcn_mfma_f32_16x16x32_bf16(af, wu2f[nt][kk], acc2[nt], 0, 0, 0);
  }
  if (act) {
    #pragma unroll
    for (int nt = 0; nt < 4; ++nt)
      #pragma unroll
      for (int rg = 0; rg < 4; ++rg) {
        const int row = tt * 16 + quad * 4 + rg;
        const int col = nt * 16 + l15;
        outf[row * 64 + col] = feat[row * 64 + col] + acc2[nt][rg] + bu2v[nt];
      }
  }
}

// -------------------------------------------------------------- launch ----
extern "C" void kernel_launch(void* const* d_in, const int* in_sizes, int n_in,
                              void* d_out, int out_size, void* d_ws, size_t ws_size,
                              hipStream_t stream)
{
  const float* feat = (const float*)d_in[0];
  const float* pos  = (const float*)d_in[1];
  const int*   nbr  = (const int*)d_in[2];
  const float* W1   = (const float*)d_in[3];
  const float* b1   = (const float*)d_in[4];
  const float* W2   = (const float*)d_in[5];
  const float* b2   = (const float*)d_in[6];
  const float* Wu1  = (const float*)d_in[7];
  const float* bu1  = (const float*)d_in[8];
  const float* Wu2  = (const float*)d_in[9];
  const float* bu2  = (const float*)d_in[10];
  float* out = (float*)d_out;

  // ws: featb 6.4M @0 | Pb 6.4M @6.4M | Q8 fp8 3.2M @12.8M | sB 6.4M @19.2M
  //   | cent4 0.8M @25.6M | swizzled weights @26.4M
  unsigned short* featb = (unsigned short*)d_ws;
  unsigned short* Pb    = (unsigned short*)((char*)d_ws + 6400000);
  unsigned char*  Q8    = (unsigned char*)((char*)d_ws + 12800000);
  unsigned short* sB    = (unsigned short*)((char*)d_ws + 19200000);
  float*          cent4 = (float*)((char*)d_ws + 25600000);
  unsigned short* w1pq  = (unsigned short*)((char*)d_ws + 26400000);
  unsigned short* w2t   = (unsigned short*)((char*)d_ws + 26416384);
  unsigned short* wu1t  = (unsigned short*)((char*)d_ws + 26424576);
  unsigned short* wu2b  = (unsigned short*)((char*)d_ws + 26440960);

  aux_kernel<<<682, 256, 0, stream>>>(pos, W1, W2, Wu1, Wu2, out + 3200000,
                                      w1pq, w2t, wu1t, wu2b);
  prep_pq_kernel<<<782, 256, 0, stream>>>(feat, pos, w1pq, featb, cent4,
                                          Pb, Q8);
  gather_kernel<<<12500, 256, 0, stream>>>(Pb, Q8, (const float4*)cent4, nbr,
                                           b1, W1, sB);
  tail_kernel<<<782, 256, 0, stream>>>(featb, sB, feat, w2t, wu1t, wu2b,
                                       b2, bu1, bu2, out);
}

// Round 11
// 132.351 us; speedup vs baseline: 1.1762x; 1.0003x over previous
//
#include <hip/hip_runtime.h>

// ETNN layer, N=50000 cells, HID=64, DEG=16 neighbors, 4 nodes/cell, sp=3.
//
// Bilinear split of the per-pair message MLP:
//   x@W1 = f_i@W1[0:64] + f_j@W1[64:128] + geom*W1[128]
// -> aux      : positions passthrough + weight pre-swizzle + CENTROIDS
// -> prep+geom: (block-split, no cross-half deps within the launch)
//               [0,782): feat->bf16, P (bf16), Q (fp8 e4m3, 64B rows)
//               [782,3907): geom[c][d] = ||cent[c]-cent[nbr[c,d]]|| fp32
//               (moves the random cent4 touches OUT of gather, overlapped
//                with prep's MFMA work)
// -> gather   : one wave per cell, one column per lane; only random traffic
//               is 16 wave-uniform 64B Q-row touches per cell; fast silu.
// -> tail     : msg = s@W2+b2; hu = silu([feat|msg]@Wu1+bu1); out = feat+hu@Wu2+bu2
//
// MFMA layouts (HW-verified): A[m=lane&15][k=quad*8+j], B[k=quad*8+j][n=lane&15],
// D[row=quad*4+reg][col=lane&15]. Transposed stages put weights in A so D cols
// land 4-consecutive per lane (packed stores). Wave-private LDS round-trips
// ordered by __threadfence_block + may_alias types.

#define DEG 16

typedef __attribute__((ext_vector_type(8))) short short8;   // 8 bf16
typedef __attribute__((ext_vector_type(4))) float f32x4;    // MFMA acc
typedef uint2 uint2_a __attribute__((may_alias));
typedef uint4 uint4_a __attribute__((may_alias));

union HbRd { uint4_a u; short8 s; };
union Frag { short8 s; uint4 u; };

__device__ __forceinline__ unsigned f2bf(float f) {
  unsigned u = __float_as_uint(f);
  return (u + 0x7FFFu + ((u >> 16) & 1u)) >> 16;   // RNE fp32->bf16
}
__device__ __forceinline__ float bf2f(unsigned bits16) {
  return __uint_as_float(bits16 << 16);
}
__device__ __forceinline__ float silu(float h) {
  return h / (1.f + __expf(-h));
}
__device__ __forceinline__ float silu_fast(float h) {
  return h * __builtin_amdgcn_rcpf(1.f + __expf(-h));
}

// ----------------------------------------------------------------- aux ----
// t<150000: positions copy | [150000,174576): weight pre-swizzle |
// [174576,224576): centroid of each cell's 4 nodes -> cent4.
__global__ __launch_bounds__(256) void aux_kernel(
    const float* __restrict__ pos,
    const float* __restrict__ W1, const float* __restrict__ W2,
    const float* __restrict__ Wu1, const float* __restrict__ Wu2,
    float* __restrict__ outpos, float* __restrict__ cent4,
    unsigned short* __restrict__ w1pq, unsigned short* __restrict__ w2t,
    unsigned short* __restrict__ wu1t, unsigned short* __restrict__ wu2b)
{
  int t = blockIdx.x * 256 + threadIdx.x;
  if (t < 150000) {
    ((float4*)outpos)[t] = ((const float4*)pos)[t];
  } else if (t < 174576) {
    const int r = t - 150000;
    if (r < 8192) {
      // w1pq: A-frags of [W1top|W1bot]^T, [mt 0..7][kk 0..1]
      const int j = r & 7, l = (r >> 3) & 15, q = (r >> 7) & 3;
      const int f = r >> 9, kk = f & 1, mt = f >> 1;
      const int k = kk * 32 + q * 8 + j;        // feat dim 0..63
      const int m = mt * 16 + l;                // pq col 0..127
      w1pq[r] = (unsigned short)f2bf(
          (m < 64) ? W1[k * 64 + m] : W1[(k + 64) * 64 + (m - 64)]);
    } else if (r < 12288) {
      // w2t: A-frags of W2^T, [mt 0..3][kk 0..1]
      const int s = r - 8192;
      const int j = s & 7, l = (s >> 3) & 15, q = (s >> 7) & 3;
      const int f = s >> 9, kk = f & 1, mt = f >> 1;
      const int k = kk * 32 + q * 8 + j;
      w2t[s] = (unsigned short)f2bf(W2[k * 64 + mt * 16 + l]);
    } else if (r < 20480) {
      // wu1t: A-frags of Wu1^T, [mt 0..3][kk 0..3]
      const int s = r - 12288;
      const int j = s & 7, l = (s >> 3) & 15, q = (s >> 7) & 3;
      const int f = s >> 9, kk = f & 3, mt = f >> 2;
      const int k = kk * 32 + q * 8 + j;        // 0..127
      wu1t[s] = (unsigned short)f2bf(Wu1[k * 64 + mt * 16 + l]);
    } else {
      // wu2b: B-frags of Wu2, [nt 0..3][kk 0..1]
      const int s = r - 20480;
      const int j = s & 7, l = (s >> 3) & 15, q = (s >> 7) & 3;
      const int f = s >> 9, kk = f & 1, nt = f >> 1;
      const int k = kk * 32 + q * 8 + j;
      wu2b[s] = (unsigned short)f2bf(Wu2[k * 64 + nt * 16 + l]);
    }
  } else if (t < 224576) {
    const int i = t - 174576;
    const float4* pp = (const float4*)(pos + 12 * i);   // 48B rows
    const float4 a = pp[0], b = pp[1], c = pp[2];
    float4 o;
    o.x = (a.x + a.w + b.z + c.y) * 0.25f;
    o.y = (a.y + b.x + b.w + c.z) * 0.25f;
    o.z = (a.z + b.y + c.x + c.w) * 0.25f;
    o.w = 0.f;
    ((float4*)cent4)[i] = o;
  }
}

// ----------------------------------------------------------- prep+geom ----
// blocks [0,782): per-16-cell tile: feat fp32->bf16 (featb + frags),
//   [P|Q]^T = Wpq^T x X^T ; P -> bf16, Q -> fp8 e4m3 (HW cvt).
// blocks [782,3907): geom: lane=(sub<<4)|d handles pair (c=gb*16+wid*4+sub, d);
//   coalesced nbr read, random cent4[nj] gather (the only random traffic),
//   geomF[c*16+d] = ||cent[c]-cent[nj]|| (fp32, coalesced store).
// No intra-launch dependence between halves (both read only aux outputs).
__global__ __launch_bounds__(256) void prep_geom_kernel(
    const float* __restrict__ feat,
    const unsigned short* __restrict__ w1pq,
    const float4* __restrict__ cent4,
    const int* __restrict__ nbr,
    unsigned short* __restrict__ featb,
    unsigned short* __restrict__ Pb, unsigned char* __restrict__ Q8,
    float* __restrict__ geomF)
{
  const int b    = blockIdx.x;
  const int lane = threadIdx.x & 63;
  const int wid  = threadIdx.x >> 6;

  if (b >= 782) {
    const int gb  = b - 782;              // 0..3124
    const int sub = lane >> 4;
    const int d   = lane & 15;
    const int c   = gb * 16 + wid * 4 + sub;   // < 50000
    const int nj  = nbr[c * DEG + d];
    const float4 ci = cent4[c];
    const float4 cj = cent4[nj];
    const float dx = ci.x - cj.x, dy = ci.y - cj.y, dz = ci.z - cj.z;
    geomF[c * DEG + d] = sqrtf(dx * dx + dy * dy + dz * dz);
    return;
  }

  const int quad = lane >> 4;
  const int l15  = lane & 15;
  const int tile = b * 4 + wid;
  const bool act = (tile < 3125);
  const int  tt  = act ? tile : 3124;
  const int  cr  = tt * 16 + l15;

  // feat rows -> bf16 frags (B-layout) + featb store
  short8 xf[2];
  #pragma unroll
  for (int kk = 0; kk < 2; ++kk) {
    const float4 f0 = *(const float4*)(feat + cr * 64 + kk * 32 + quad * 8);
    const float4 f1 = *(const float4*)(feat + cr * 64 + kk * 32 + quad * 8 + 4);
    Frag v;
    v.s[0] = (short)f2bf(f0.x); v.s[1] = (short)f2bf(f0.y);
    v.s[2] = (short)f2bf(f0.z); v.s[3] = (short)f2bf(f0.w);
    v.s[4] = (short)f2bf(f1.x); v.s[5] = (short)f2bf(f1.y);
    v.s[6] = (short)f2bf(f1.z); v.s[7] = (short)f2bf(f1.w);
    xf[kk] = v.s;
    if (act) *(uint4*)(featb + cr * 64 + kk * 32 + quad * 8) = v.u;
  }

  short8 wf[8][2];
  #pragma unroll
  for (int mt = 0; mt < 8; ++mt)
    #pragma unroll
    for (int kk = 0; kk < 2; ++kk)
      wf[mt][kk] = *(const short8*)(w1pq + (((mt * 2 + kk) * 4 + quad) << 7) + l15 * 8);

  f32x4 acc[8] = {};
  #pragma unroll
  for (int kk = 0; kk < 2; ++kk)
    #pragma unroll
    for (int mt = 0; mt < 8; ++mt)
      acc[mt] = __builtin_amdgcn_mfma_f32_16x16x32_bf16(wf[mt][kk], xf[kk], acc[mt], 0, 0, 0);

  if (act) {
    #pragma unroll
    for (int mt = 0; mt < 4; ++mt) {       // P: bf16
      uint2 pk;
      pk.x = f2bf(acc[mt][0]) | (f2bf(acc[mt][1]) << 16);
      pk.y = f2bf(acc[mt][2]) | (f2bf(acc[mt][3]) << 16);
      *(uint2*)(Pb + cr * 64 + mt * 16 + quad * 4) = pk;
    }
    #pragma unroll
    for (int mt = 4; mt < 8; ++mt) {       // Q: fp8 e4m3 (HW cvt pair)
      int w = __builtin_amdgcn_cvt_pk_fp8_f32(acc[mt][0], acc[mt][1], 0, false);
      w = __builtin_amdgcn_cvt_pk_fp8_f32(acc[mt][2], acc[mt][3], w, true);
      *(unsigned int*)(Q8 + cr * 64 + (mt - 4) * 16 + quad * 4) = (unsigned)w;
    }
  }
}

// -------------------------------------------------------------- gather ----
// One wave per cell, one column per lane. nbr ids + precomputed geom are
// wave-uniform per d: broadcast via readlane. Only random traffic: 16
// wave-uniform 64B fp8 Q-row loads (one L1 line each). Fast silu via rcp.
__global__ __launch_bounds__(256) void gather_kernel(
    const unsigned short* __restrict__ Pb,
    const unsigned char* __restrict__ Q8,
    const float* __restrict__ geomF,
    const int* __restrict__ nbr,
    const float* __restrict__ b1, const float* __restrict__ W1,
    unsigned short* __restrict__ sB)
{
  const int lane = threadIdx.x & 63;
  const int wid  = threadIdx.x >> 6;
  const int c    = blockIdx.x * 4 + wid;   // 12500 blocks x 4 waves = 50000

  // lanes 0..15 carry the 16 neighbor ids / geoms (replicated x4)
  const int   nj = nbr[c * DEG + (lane & 15)];
  const float gv = geomF[c * DEG + (lane & 15)];

  // per-column constants (lane = column)
  const float pcb = bf2f(Pb[c * 64 + lane]) + b1[lane];
  const float wl  = W1[8192 + lane];

  float acc = 0.f;
  #pragma unroll
  for (int d = 0; d < DEG; ++d) {
    const int   nd = __builtin_amdgcn_readlane(nj, d);
    const float gd = __uint_as_float(
        __builtin_amdgcn_readlane((int)__float_as_uint(gv), d));
    const float qv = __builtin_amdgcn_cvt_f32_fp8((int)Q8[nd * 64 + lane], 0);
    acc += silu_fast(pcb + qv + gd * wl);
  }

  sB[c * 64 + lane] = (unsigned short)f2bf(acc * 0.0625f);
}

// ---------------------------------------------------------------- tail ----
// Per 16-cell tile: msg^T = W2^T x s^T (+b2) -> LDS; hu^T = Wu1^T x [feat|msg]^T
// (+bu1, silu) -> LDS; out = hu x Wu2 + bu2 + feat.
__global__ __launch_bounds__(256) void tail_kernel(
    const unsigned short* __restrict__ featb,
    const unsigned short* __restrict__ sB,
    const float* __restrict__ feat,
    const unsigned short* __restrict__ w2t,
    const unsigned short* __restrict__ wu1t,
    const unsigned short* __restrict__ wu2b,
    const float* __restrict__ b2, const float* __restrict__ bu1,
    const float* __restrict__ bu2,
    float* __restrict__ outf)
{
  __shared__ uint4 smem[4 * 288];   // per wave: Msg 16x144B + Hb 16x144B
  const int lane = threadIdx.x & 63;
  const int wid  = threadIdx.x >> 6;
  const int quad = lane >> 4;
  const int l15  = lane & 15;
  char* Msg = (char*)(smem + wid * 288);
  char* Hb  = Msg + 2304;

  short8 w2f[4][2];
  #pragma unroll
  for (int mt = 0; mt < 4; ++mt)
    #pragma unroll
    for (int kk = 0; kk < 2; ++kk)
      w2f[mt][kk] = *(const short8*)(w2t + (((mt * 2 + kk) * 4 + quad) << 7) + l15 * 8);
  short8 wu1f[4][4];
  #pragma unroll
  for (int mt = 0; mt < 4; ++mt)
    #pragma unroll
    for (int kk = 0; kk < 4; ++kk)
      wu1f[mt][kk] = *(const short8*)(wu1t + (((mt * 4 + kk) * 4 + quad) << 7) + l15 * 8);
  short8 wu2f[4][2];
  #pragma unroll
  for (int nt = 0; nt < 4; ++nt)
    #pragma unroll
    for (int kk = 0; kk < 2; ++kk)
      wu2f[nt][kk] = *(const short8*)(wu2b + (((nt * 2 + kk) * 4 + quad) << 7) + l15 * 8);

  f32x4 b2f[4], bu1f[4];
  #pragma unroll
  for (int mt = 0; mt < 4; ++mt) {
    b2f[mt]  = *(const f32x4*)(b2  + mt * 16 + quad * 4);
    bu1f[mt] = *(const f32x4*)(bu1 + mt * 16 + quad * 4);
  }
  float bu2v[4];
  #pragma unroll
  for (int nt = 0; nt < 4; ++nt) bu2v[nt] = bu2[nt * 16 + l15];

  const int tile = blockIdx.x * 4 + wid;
  const bool act = (tile < 3125);
  const int  tt  = act ? tile : 3124;
  const int  cr  = tt * 16 + l15;

  // stage 1: msg^T = W2^T x s^T (+b2)
  f32x4 accm[4] = {};
  #pragma unroll
  for (int kk = 0; kk < 2; ++kk) {
    const short8 bf = *(const short8*)(sB + cr * 64 + kk * 32 + quad * 8);
    #pragma unroll
    for (int mt = 0; mt < 4; ++mt)
      accm[mt] = __builtin_amdgcn_mfma_f32_16x16x32_bf16(w2f[mt][kk], bf, accm[mt], 0, 0, 0);
  }
  #pragma unroll
  for (int mt = 0; mt < 4; ++mt) {
    uint2 pk;
    pk.x = f2bf(accm[mt][0] + b2f[mt][0]) | (f2bf(accm[mt][1] + b2f[mt][1]) << 16);
    pk.y = f2bf(accm[mt][2] + b2f[mt][2]) | (f2bf(accm[mt][3] + b2f[mt][3]) << 16);
    *(uint2_a*)(Msg + l15 * 144 + mt * 32 + quad * 8) = pk;
  }
  __threadfence_block();

  // stage 2: hu^T = Wu1^T x U^T, U = [feat | msg]
  f32x4 accu[4] = {};
  #pragma unroll
  for (int kk = 0; kk < 4; ++kk) {
    short8 bf;
    if (kk < 2) {
      bf = *(const short8*)(featb + cr * 64 + kk * 32 + quad * 8);
    } else {
      HbRd t; t.u = *(const uint4_a*)(Msg + l15 * 144 + (kk - 2) * 64 + quad * 16);
      bf = t.s;
    }
    #pragma unroll
    for (int mt = 0; mt < 4; ++mt)
      accu[mt] = __builtin_amdgcn_mfma_f32_16x16x32_bf16(wu1f[mt][kk], bf, accu[mt], 0, 0, 0);
  }
  #pragma unroll
  for (int mt = 0; mt < 4; ++mt) {
    float sv[4];
    #pragma unroll
    for (int rg = 0; rg < 4; ++rg)
      sv[rg] = silu(accu[mt][rg] + bu1f[mt][rg]);
    uint2 pk;
    pk.x = f2bf(sv[0]) | (f2bf(sv[1]) << 16);
    pk.y = f2bf(sv[2]) | (f2bf(sv[3]) << 16);
    *(uint2_a*)(Hb + l15 * 144 + mt * 32 + quad * 8) = pk;
  }
  __threadfence_block();

  // stage 3: out = hu x Wu2 + bu2 + feat
  f32x4 acc2[4] = {};
  #pragma unroll
  for (int kk = 0; kk < 2; ++kk) {
    HbRd t; t.u = *(const uint4_a*)(Hb + l15 * 144 + kk * 64 + quad * 16);
    const short8 af = t.s;
    #pragma unroll
    for (int nt = 0; nt < 4; ++nt)
      acc2[nt] = __builtin_amdgcn_mfma_f32_16x16x32_bf16(af, wu2f[nt][kk], acc2[nt], 0, 0, 0);
  }
  if (act) {
    #pragma unroll
    for (int nt = 0; nt < 4; ++nt)
      #pragma unroll
      for (int rg = 0; rg < 4; ++rg) {
        const int row = tt * 16 + quad * 4 + rg;
        const int col = nt * 16 + l15;
        outf[row * 64 + col] = feat[row * 64 + col] + acc2[nt][rg] + bu2v[nt];
      }
  }
}

// -------------------------------------------------------------- launch ----
extern "C" void kernel_launch(void* const* d_in, const int* in_sizes, int n_in,
                              void* d_out, int out_size, void* d_ws, size_t ws_size,
                              hipStream_t stream)
{
  const float* feat = (const float*)d_in[0];
  const float* pos  = (const float*)d_in[1];
  const int*   nbr  = (const int*)d_in[2];
  const float* W1   = (const float*)d_in[3];
  const float* b1   = (const float*)d_in[4];
  const float* W2   = (const float*)d_in[5];
  const float* b2   = (const float*)d_in[6];
  const float* Wu1  = (const float*)d_in[7];
  const float* bu1  = (const float*)d_in[8];
  const float* Wu2  = (const float*)d_in[9];
  const float* bu2  = (const float*)d_in[10];
  float* out = (float*)d_out;

  // ws: featb 6.4M @0 | Pb 6.4M @6.4M | Q8 fp8 3.2M @12.8M | geomF 3.2M @16M
  //   | sB 6.4M @19.2M | cent4 0.8M @25.6M | swizzled weights @26.4M
  unsigned short* featb = (unsigned short*)d_ws;
  unsigned short* Pb    = (unsigned short*)((char*)d_ws + 6400000);
  unsigned char*  Q8    = (unsigned char*)((char*)d_ws + 12800000);
  float*          geomF = (float*)((char*)d_ws + 16000000);
  unsigned short* sB    = (unsigned short*)((char*)d_ws + 19200000);
  float*          cent4 = (float*)((char*)d_ws + 25600000);
  unsigned short* w1pq  = (unsigned short*)((char*)d_ws + 26400000);
  unsigned short* w2t   = (unsigned short*)((char*)d_ws + 26416384);
  unsigned short* wu1t  = (unsigned short*)((char*)d_ws + 26424576);
  unsigned short* wu2b  = (unsigned short*)((char*)d_ws + 26440960);

  aux_kernel<<<878, 256, 0, stream>>>(pos, W1, W2, Wu1, Wu2, out + 3200000,
                                      cent4, w1pq, w2t, wu1t, wu2b);
  prep_geom_kernel<<<3907, 256, 0, stream>>>(feat, w1pq, (const float4*)cent4,
                                             nbr, featb, Pb, Q8, geomF);
  gather_kernel<<<12500, 256, 0, stream>>>(Pb, Q8, geomF, nbr, b1, W1, sB);
  tail_kernel<<<782, 256, 0, stream>>>(featb, sB, feat, w2t, wu1t, wu2b,
                                       b2, bu1, bu2, out);
}

// Round 12
// 121.811 us; speedup vs baseline: 1.2779x; 1.0865x over previous
//
#include <hip/hip_runtime.h>

// ETNN layer, N=50000 cells, HID=64, DEG=16 neighbors, 4 nodes/cell, sp=3.
//
// Bilinear split of the per-pair message MLP:
//   x@W1 = f_i@W1[0:64] + f_j@W1[64:128] + geom*W1[128]
// -> aux      : positions passthrough + weight pre-swizzle + centroids
// -> prep+geom: (block-split) [0,782): feat->bf16, P (bf16), Q (fp8 e4m3);
//               [782,3907): geom[c][d] = ||cent[c]-cent[nbr[c,d]]||
// -> msg_tail : FUSED. Block = one 16-cell tile (3125 blocks, 4 waves).
//               Phase A (per wave, 4 cells): s[c] = mean_d silu(P+Q[nbr]+g*w1L+b1)
//                 -> LDS s-tile. nbr/geom rows via readfirstlane-uniform
//                 pointers (s_load); only random traffic = 16 uniform 64B
//                 fp8 Q-row touches per cell.
//               Phase B (tail split by wave, wave w owns mt/nt = w):
//                 msg^T = W2^T x s^T (+b2) -> LDS; hu^T = Wu1^T x [feat|msg]^T
//                 (+bu1, silu) -> LDS; out = hu x Wu2 + bu2 + feat.
//               __syncthreads() between stages (block-shared LDS).
//
// MFMA layouts (HW-verified): A[m=lane&15][k=quad*8+j], B[k=quad*8+j][n=lane&15],
// D[row=quad*4+reg][col=lane&15]. Transposed stages put weights in A so D cols
// land 4-consecutive per lane (packed stores).

#define DEG 16

typedef __attribute__((ext_vector_type(8))) short short8;   // 8 bf16
typedef __attribute__((ext_vector_type(4))) float f32x4;    // MFMA acc
typedef uint2 uint2_a __attribute__((may_alias));
typedef uint4 uint4_a __attribute__((may_alias));

union HbRd { uint4_a u; short8 s; };
union Frag { short8 s; uint4 u; };

__device__ __forceinline__ unsigned f2bf(float f) {
  unsigned u = __float_as_uint(f);
  return (u + 0x7FFFu + ((u >> 16) & 1u)) >> 16;   // RNE fp32->bf16
}
__device__ __forceinline__ float bf2f(unsigned bits16) {
  return __uint_as_float(bits16 << 16);
}
__device__ __forceinline__ float silu(float h) {
  return h / (1.f + __expf(-h));
}
__device__ __forceinline__ float silu_fast(float h) {
  return h * __builtin_amdgcn_rcpf(1.f + __expf(-h));
}

// ----------------------------------------------------------------- aux ----
// t<150000: positions copy | [150000,174576): weight pre-swizzle |
// [174576,224576): centroid of each cell's 4 nodes -> cent4.
__global__ __launch_bounds__(256) void aux_kernel(
    const float* __restrict__ pos,
    const float* __restrict__ W1, const float* __restrict__ W2,
    const float* __restrict__ Wu1, const float* __restrict__ Wu2,
    float* __restrict__ outpos, float* __restrict__ cent4,
    unsigned short* __restrict__ w1pq, unsigned short* __restrict__ w2t,
    unsigned short* __restrict__ wu1t, unsigned short* __restrict__ wu2b)
{
  int t = blockIdx.x * 256 + threadIdx.x;
  if (t < 150000) {
    ((float4*)outpos)[t] = ((const float4*)pos)[t];
  } else if (t < 174576) {
    const int r = t - 150000;
    if (r < 8192) {
      // w1pq: A-frags of [W1top|W1bot]^T, [mt 0..7][kk 0..1]
      const int j = r & 7, l = (r >> 3) & 15, q = (r >> 7) & 3;
      const int f = r >> 9, kk = f & 1, mt = f >> 1;
      const int k = kk * 32 + q * 8 + j;        // feat dim 0..63
      const int m = mt * 16 + l;                // pq col 0..127
      w1pq[r] = (unsigned short)f2bf(
          (m < 64) ? W1[k * 64 + m] : W1[(k + 64) * 64 + (m - 64)]);
    } else if (r < 12288) {
      // w2t: A-frags of W2^T, [mt 0..3][kk 0..1]
      const int s = r - 8192;
      const int j = s & 7, l = (s >> 3) & 15, q = (s >> 7) & 3;
      const int f = s >> 9, kk = f & 1, mt = f >> 1;
      const int k = kk * 32 + q * 8 + j;
      w2t[s] = (unsigned short)f2bf(W2[k * 64 + mt * 16 + l]);
    } else if (r < 20480) {
      // wu1t: A-frags of Wu1^T, [mt 0..3][kk 0..3]
      const int s = r - 12288;
      const int j = s & 7, l = (s >> 3) & 15, q = (s >> 7) & 3;
      const int f = s >> 9, kk = f & 3, mt = f >> 2;
      const int k = kk * 32 + q * 8 + j;        // 0..127
      wu1t[s] = (unsigned short)f2bf(Wu1[k * 64 + mt * 16 + l]);
    } else {
      // wu2b: B-frags of Wu2, [nt 0..3][kk 0..1]
      const int s = r - 20480;
      const int j = s & 7, l = (s >> 3) & 15, q = (s >> 7) & 3;
      const int f = s >> 9, kk = f & 1, nt = f >> 1;
      const int k = kk * 32 + q * 8 + j;
      wu2b[s] = (unsigned short)f2bf(Wu2[k * 64 + nt * 16 + l]);
    }
  } else if (t < 224576) {
    const int i = t - 174576;
    const float4* pp = (const float4*)(pos + 12 * i);   // 48B rows
    const float4 a = pp[0], b = pp[1], c = pp[2];
    float4 o;
    o.x = (a.x + a.w + b.z + c.y) * 0.25f;
    o.y = (a.y + b.x + b.w + c.z) * 0.25f;
    o.z = (a.z + b.y + c.x + c.w) * 0.25f;
    o.w = 0.f;
    ((float4*)cent4)[i] = o;
  }
}

// ----------------------------------------------------------- prep+geom ----
// blocks [0,782): per-16-cell tile: feat fp32->bf16 (featb + frags),
//   [P|Q]^T = Wpq^T x X^T ; P -> bf16, Q -> fp8 e4m3 (HW cvt).
// blocks [782,3907): geom[c][d] = ||cent[c]-cent[nbr[c,d]]|| (fp32).
// No intra-launch dependence between halves (both read only aux outputs).
__global__ __launch_bounds__(256) void prep_geom_kernel(
    const float* __restrict__ feat,
    const unsigned short* __restrict__ w1pq,
    const float4* __restrict__ cent4,
    const int* __restrict__ nbr,
    unsigned short* __restrict__ featb,
    unsigned short* __restrict__ Pb, unsigned char* __restrict__ Q8,
    float* __restrict__ geomF)
{
  const int b    = blockIdx.x;
  const int lane = threadIdx.x & 63;
  const int wid  = threadIdx.x >> 6;

  if (b >= 782) {
    const int gb  = b - 782;              // 0..3124
    const int sub = lane >> 4;
    const int d   = lane & 15;
    const int c   = gb * 16 + wid * 4 + sub;   // < 50000
    const int nj  = nbr[c * DEG + d];
    const float4 ci = cent4[c];
    const float4 cj = cent4[nj];
    const float dx = ci.x - cj.x, dy = ci.y - cj.y, dz = ci.z - cj.z;
    geomF[c * DEG + d] = sqrtf(dx * dx + dy * dy + dz * dz);
    return;
  }

  const int quad = lane >> 4;
  const int l15  = lane & 15;
  const int tile = b * 4 + wid;
  const bool act = (tile < 3125);
  const int  tt  = act ? tile : 3124;
  const int  cr  = tt * 16 + l15;

  // feat rows -> bf16 frags (B-layout) + featb store
  short8 xf[2];
  #pragma unroll
  for (int kk = 0; kk < 2; ++kk) {
    const float4 f0 = *(const float4*)(feat + cr * 64 + kk * 32 + quad * 8);
    const float4 f1 = *(const float4*)(feat + cr * 64 + kk * 32 + quad * 8 + 4);
    Frag v;
    v.s[0] = (short)f2bf(f0.x); v.s[1] = (short)f2bf(f0.y);
    v.s[2] = (short)f2bf(f0.z); v.s[3] = (short)f2bf(f0.w);
    v.s[4] = (short)f2bf(f1.x); v.s[5] = (short)f2bf(f1.y);
    v.s[6] = (short)f2bf(f1.z); v.s[7] = (short)f2bf(f1.w);
    xf[kk] = v.s;
    if (act) *(uint4*)(featb + cr * 64 + kk * 32 + quad * 8) = v.u;
  }

  short8 wf[8][2];
  #pragma unroll
  for (int mt = 0; mt < 8; ++mt)
    #pragma unroll
    for (int kk = 0; kk < 2; ++kk)
      wf[mt][kk] = *(const short8*)(w1pq + (((mt * 2 + kk) * 4 + quad) << 7) + l15 * 8);

  f32x4 acc[8] = {};
  #pragma unroll
  for (int kk = 0; kk < 2; ++kk)
    #pragma unroll
    for (int mt = 0; mt < 8; ++mt)
      acc[mt] = __builtin_amdgcn_mfma_f32_16x16x32_bf16(wf[mt][kk], xf[kk], acc[mt], 0, 0, 0);

  if (act) {
    #pragma unroll
    for (int mt = 0; mt < 4; ++mt) {       // P: bf16
      uint2 pk;
      pk.x = f2bf(acc[mt][0]) | (f2bf(acc[mt][1]) << 16);
      pk.y = f2bf(acc[mt][2]) | (f2bf(acc[mt][3]) << 16);
      *(uint2*)(Pb + cr * 64 + mt * 16 + quad * 4) = pk;
    }
    #pragma unroll
    for (int mt = 4; mt < 8; ++mt) {       // Q: fp8 e4m3 (HW cvt pair)
      int w = __builtin_amdgcn_cvt_pk_fp8_f32(acc[mt][0], acc[mt][1], 0, false);
      w = __builtin_amdgcn_cvt_pk_fp8_f32(acc[mt][2], acc[mt][3], w, true);
      *(unsigned int*)(Q8 + cr * 64 + (mt - 4) * 16 + quad * 4) = (unsigned)w;
    }
  }
}

// ------------------------------------------------------------ msg_tail ----
// One block per 16-cell tile (3125 blocks, 4 waves).
// Phase A: wave w gathers cells tile*16+w*4 .. +3; one column per lane;
//   nbr/geom rows via readfirstlane-uniform pointers (scalar loads);
//   s rows -> LDS sTile (bf16, 144B stride).
// Phase B: tail split by wave (wave w owns mt/nt = w), LDS barriers between.
__global__ __launch_bounds__(256) void msg_tail_kernel(
    const unsigned short* __restrict__ featb,
    const unsigned short* __restrict__ Pb,
    const unsigned char* __restrict__ Q8,
    const float* __restrict__ geomF,
    const int* __restrict__ nbr,
    const float* __restrict__ feat,
    const unsigned short* __restrict__ w2t,
    const unsigned short* __restrict__ wu1t,
    const unsigned short* __restrict__ wu2b,
    const float* __restrict__ b1, const float* __restrict__ W1,
    const float* __restrict__ b2, const float* __restrict__ bu1,
    const float* __restrict__ bu2,
    float* __restrict__ outf)
{
  __shared__ uint4 smem[432];   // sTile 16x144B | Msg 16x144B | Hb 16x144B
  char* sT  = (char*)smem;
  char* Msg = sT + 2304;
  char* Hb  = sT + 4608;

  const int lane = threadIdx.x & 63;
  const int wid  = threadIdx.x >> 6;
  const int quad = lane >> 4;
  const int l15  = lane & 15;
  const int tile = blockIdx.x;

  // ---- Phase A: gather 4 cells per wave ----
  const float b1l = b1[lane];
  const float wl  = W1[8192 + lane];

  #pragma unroll
  for (int i = 0; i < 4; ++i) {
    const int c  = tile * 16 + wid * 4 + i;
    const int cs = __builtin_amdgcn_readfirstlane(c);
    const int*   nrow = nbr   + cs * DEG;
    const float* grow = geomF + cs * DEG;

    const float pcb = bf2f(Pb[cs * 64 + lane]) + b1l;

    float acc = 0.f;
    #pragma unroll
    for (int d = 0; d < DEG; ++d) {
      const int   nd = nrow[d];                    // uniform -> s_load
      const float gd = grow[d];                    // uniform -> s_load
      const float qv = __builtin_amdgcn_cvt_f32_fp8((int)Q8[nd * 64 + lane], 0);
      acc += silu_fast(pcb + qv + gd * wl);
    }
    ((unsigned short*)(sT + (wid * 4 + i) * 144))[lane] =
        (unsigned short)f2bf(acc * 0.0625f);
  }

  // wave w's weight frags (mt/nt = wid only)
  short8 w2f[2], wu1f[4], wu2f[2];
  #pragma unroll
  for (int kk = 0; kk < 2; ++kk)
    w2f[kk]  = *(const short8*)(w2t  + (((wid * 2 + kk) * 4 + quad) << 7) + l15 * 8);
  #pragma unroll
  for (int kk = 0; kk < 4; ++kk)
    wu1f[kk] = *(const short8*)(wu1t + (((wid * 4 + kk) * 4 + quad) << 7) + l15 * 8);
  #pragma unroll
  for (int kk = 0; kk < 2; ++kk)
    wu2f[kk] = *(const short8*)(wu2b + (((wid * 2 + kk) * 4 + quad) << 7) + l15 * 8);

  const f32x4 b2f  = *(const f32x4*)(b2  + wid * 16 + quad * 4);
  const f32x4 bu1f = *(const f32x4*)(bu1 + wid * 16 + quad * 4);
  const float bu2v = bu2[wid * 16 + l15];

  __syncthreads();

  // ---- stage 1: msg^T = W2^T x s^T (+b2), mt = wid ----
  f32x4 accm = {};
  #pragma unroll
  for (int kk = 0; kk < 2; ++kk) {
    HbRd t; t.u = *(const uint4_a*)(sT + l15 * 144 + kk * 64 + quad * 16);
    accm = __builtin_amdgcn_mfma_f32_16x16x32_bf16(w2f[kk], t.s, accm, 0, 0, 0);
  }
  __syncthreads();   // all sTile reads done before Msg overwrites... (disjoint buffers, but keep ordering simple)
  {
    uint2 pk;
    pk.x = f2bf(accm[0] + b2f[0]) | (f2bf(accm[1] + b2f[1]) << 16);
    pk.y = f2bf(accm[2] + b2f[2]) | (f2bf(accm[3] + b2f[3]) << 16);
    *(uint2_a*)(Msg + l15 * 144 + wid * 32 + quad * 8) = pk;
  }
  __syncthreads();

  // ---- stage 2: hu^T = Wu1^T x [feat|msg]^T (+bu1, silu), mt = wid ----
  const int cr = tile * 16 + l15;
  f32x4 accu = {};
  #pragma unroll
  for (int kk = 0; kk < 4; ++kk) {
    short8 bf;
    if (kk < 2) {
      bf = *(const short8*)(featb + cr * 64 + kk * 32 + quad * 8);
    } else {
      HbRd t; t.u = *(const uint4_a*)(Msg + l15 * 144 + (kk - 2) * 64 + quad * 16);
      bf = t.s;
    }
    accu = __builtin_amdgcn_mfma_f32_16x16x32_bf16(wu1f[kk], bf, accu, 0, 0, 0);
  }
  {
    float sv[4];
    #pragma unroll
    for (int rg = 0; rg < 4; ++rg)
      sv[rg] = silu(accu[rg] + bu1f[rg]);
    uint2 pk;
    pk.x = f2bf(sv[0]) | (f2bf(sv[1]) << 16);
    pk.y = f2bf(sv[2]) | (f2bf(sv[3]) << 16);
    *(uint2_a*)(Hb + l15 * 144 + wid * 32 + quad * 8) = pk;
  }
  __syncthreads();

  // ---- stage 3: out = hu x Wu2 + bu2 + feat, nt = wid ----
  f32x4 acc2 = {};
  #pragma unroll
  for (int kk = 0; kk < 2; ++kk) {
    HbRd t; t.u = *(const uint4_a*)(Hb + l15 * 144 + kk * 64 + quad * 16);
    acc2 = __builtin_amdgcn_mfma_f32_16x16x32_bf16(t.s, wu2f[kk], acc2, 0, 0, 0);
  }
  #pragma unroll
  for (int rg = 0; rg < 4; ++rg) {
    const int row = tile * 16 + quad * 4 + rg;
    const int col = wid * 16 + l15;
    outf[row * 64 + col] = feat[row * 64 + col] + acc2[rg] + bu2v;
  }
}

// -------------------------------------------------------------- launch ----
extern "C" void kernel_launch(void* const* d_in, const int* in_sizes, int n_in,
                              void* d_out, int out_size, void* d_ws, size_t ws_size,
                              hipStream_t stream)
{
  const float* feat = (const float*)d_in[0];
  const float* pos  = (const float*)d_in[1];
  const int*   nbr  = (const int*)d_in[2];
  const float* W1   = (const float*)d_in[3];
  const float* b1   = (const float*)d_in[4];
  const float* W2   = (const float*)d_in[5];
  const float* b2   = (const float*)d_in[6];
  const float* Wu1  = (const float*)d_in[7];
  const float* bu1  = (const float*)d_in[8];
  const float* Wu2  = (const float*)d_in[9];
  const float* bu2  = (const float*)d_in[10];
  float* out = (float*)d_out;

  // ws: featb 6.4M @0 | Pb 6.4M @6.4M | Q8 fp8 3.2M @12.8M | geomF 3.2M @16M
  //   | cent4 0.8M @25.6M | swizzled weights @26.4M
  unsigned short* featb = (unsigned short*)d_ws;
  unsigned short* Pb    = (unsigned short*)((char*)d_ws + 6400000);
  unsigned char*  Q8    = (unsigned char*)((char*)d_ws + 12800000);
  float*          geomF = (float*)((char*)d_ws + 16000000);
  float*          cent4 = (float*)((char*)d_ws + 25600000);
  unsigned short* w1pq  = (unsigned short*)((char*)d_ws + 26400000);
  unsigned short* w2t   = (unsigned short*)((char*)d_ws + 26416384);
  unsigned short* wu1t  = (unsigned short*)((char*)d_ws + 26424576);
  unsigned short* wu2b  = (unsigned short*)((char*)d_ws + 26440960);

  aux_kernel<<<878, 256, 0, stream>>>(pos, W1, W2, Wu1, Wu2, out + 3200000,
                                      cent4, w1pq, w2t, wu1t, wu2b);
  prep_geom_kernel<<<3907, 256, 0, stream>>>(feat, w1pq, (const float4*)cent4,
                                             nbr, featb, Pb, Q8, geomF);
  msg_tail_kernel<<<3125, 256, 0, stream>>>(featb, Pb, Q8, geomF, nbr, feat,
                                            w2t, wu1t, wu2b,
                                            b1, W1, b2, bu1, bu2, out);
}

// Round 13
// 120.418 us; speedup vs baseline: 1.2927x; 1.0116x over previous
//
#include <hip/hip_runtime.h>

// ETNN layer, N=50000 cells, HID=64, DEG=16 neighbors, 4 nodes/cell, sp=3.
//
// Bilinear split of the per-pair message MLP:
//   x@W1 = f_i@W1[0:64] + f_j@W1[64:128] + geom*W1[128]
// -> aux     : positions passthrough + weight pre-swizzle + centroids
// -> prep    : feat fp32->bf16 (featb) + Q = feat@W1bot as fp8 e4m3 (64B rows)
// -> msg_tail: FUSED, block = one 16-cell tile (3125 blocks, 4 waves):
//      phase 0: P-tile^T = W1top^T x X^T (MFMA from featb) -> LDS (bf16)
//      phase A: per wave 4 cells: geom inline (cent4[c] scalar + cent4[nbr]
//               lane-gather + readlane bcast), s = mean_d silu(P+Q[nbr]+g*w1L+b1)
//               -> overwrites own P rows in LDS
//      phase B: msg^T = W2^T x s^T (+b2) -> LDS; hu^T = Wu1^T x [feat|msg]^T
//               (+bu1, silu) -> LDS; out = hu x Wu2 + bu2 + feat.
//
// MFMA layouts (HW-verified): A[m=lane&15][k=quad*8+j], B[k=quad*8+j][n=lane&15],
// D[row=quad*4+reg][col=lane&15].

#define DEG 16

typedef __attribute__((ext_vector_type(8))) short short8;   // 8 bf16
typedef __attribute__((ext_vector_type(4))) float f32x4;    // MFMA acc
typedef uint2 uint2_a __attribute__((may_alias));
typedef uint4 uint4_a __attribute__((may_alias));
typedef unsigned short ushort_a __attribute__((may_alias));

union HbRd { uint4_a u; short8 s; };
union Frag { short8 s; uint4 u; };

__device__ __forceinline__ unsigned f2bf(float f) {
  unsigned u = __float_as_uint(f);
  return (u + 0x7FFFu + ((u >> 16) & 1u)) >> 16;   // RNE fp32->bf16
}
__device__ __forceinline__ float bf2f(unsigned bits16) {
  return __uint_as_float(bits16 << 16);
}
__device__ __forceinline__ float silu(float h) {
  return h / (1.f + __expf(-h));
}
__device__ __forceinline__ float silu_fast(float h) {
  return h * __builtin_amdgcn_rcpf(1.f + __expf(-h));
}

// ----------------------------------------------------------------- aux ----
// t<150000: positions copy | [150000,174576): weight pre-swizzle |
// [174576,224576): centroid of each cell's 4 nodes -> cent4.
__global__ __launch_bounds__(256) void aux_kernel(
    const float* __restrict__ pos,
    const float* __restrict__ W1, const float* __restrict__ W2,
    const float* __restrict__ Wu1, const float* __restrict__ Wu2,
    float* __restrict__ outpos, float* __restrict__ cent4,
    unsigned short* __restrict__ w1pq, unsigned short* __restrict__ w2t,
    unsigned short* __restrict__ wu1t, unsigned short* __restrict__ wu2b)
{
  int t = blockIdx.x * 256 + threadIdx.x;
  if (t < 150000) {
    ((float4*)outpos)[t] = ((const float4*)pos)[t];
  } else if (t < 174576) {
    const int r = t - 150000;
    if (r < 8192) {
      // w1pq: A-frags of [W1top|W1bot]^T, [mt 0..7][kk 0..1]
      const int j = r & 7, l = (r >> 3) & 15, q = (r >> 7) & 3;
      const int f = r >> 9, kk = f & 1, mt = f >> 1;
      const int k = kk * 32 + q * 8 + j;        // feat dim 0..63
      const int m = mt * 16 + l;                // pq col 0..127
      w1pq[r] = (unsigned short)f2bf(
          (m < 64) ? W1[k * 64 + m] : W1[(k + 64) * 64 + (m - 64)]);
    } else if (r < 12288) {
      // w2t: A-frags of W2^T, [mt 0..3][kk 0..1]
      const int s = r - 8192;
      const int j = s & 7, l = (s >> 3) & 15, q = (s >> 7) & 3;
      const int f = s >> 9, kk = f & 1, mt = f >> 1;
      const int k = kk * 32 + q * 8 + j;
      w2t[s] = (unsigned short)f2bf(W2[k * 64 + mt * 16 + l]);
    } else if (r < 20480) {
      // wu1t: A-frags of Wu1^T, [mt 0..3][kk 0..3]
      const int s = r - 12288;
      const int j = s & 7, l = (s >> 3) & 15, q = (s >> 7) & 3;
      const int f = s >> 9, kk = f & 3, mt = f >> 2;
      const int k = kk * 32 + q * 8 + j;        // 0..127
      wu1t[s] = (unsigned short)f2bf(Wu1[k * 64 + mt * 16 + l]);
    } else {
      // wu2b: B-frags of Wu2, [nt 0..3][kk 0..1]
      const int s = r - 20480;
      const int j = s & 7, l = (s >> 3) & 15, q = (s >> 7) & 3;
      const int f = s >> 9, kk = f & 1, nt = f >> 1;
      const int k = kk * 32 + q * 8 + j;
      wu2b[s] = (unsigned short)f2bf(Wu2[k * 64 + nt * 16 + l]);
    }
  } else if (t < 224576) {
    const int i = t - 174576;
    const float4* pp = (const float4*)(pos + 12 * i);   // 48B rows
    const float4 a = pp[0], b = pp[1], c = pp[2];
    float4 o;
    o.x = (a.x + a.w + b.z + c.y) * 0.25f;
    o.y = (a.y + b.x + b.w + c.z) * 0.25f;
    o.z = (a.z + b.y + c.x + c.w) * 0.25f;
    o.w = 0.f;
    ((float4*)cent4)[i] = o;
  }
}

// ---------------------------------------------------------------- prep ----
// Per-16-cell tile (782 blocks): feat fp32->bf16 (featb + frags),
// Q^T = W1bot^T x X^T -> fp8 e4m3 (HW cvt), 64B rows.
__global__ __launch_bounds__(256) void prep_kernel(
    const float* __restrict__ feat,
    const unsigned short* __restrict__ w1pq,
    unsigned short* __restrict__ featb,
    unsigned char* __restrict__ Q8)
{
  const int lane = threadIdx.x & 63;
  const int wid  = threadIdx.x >> 6;
  const int quad = lane >> 4;
  const int l15  = lane & 15;
  const int tile = blockIdx.x * 4 + wid;
  const bool act = (tile < 3125);
  const int  tt  = act ? tile : 3124;
  const int  cr  = tt * 16 + l15;

  // feat rows -> bf16 frags (B-layout) + featb store
  short8 xf[2];
  #pragma unroll
  for (int kk = 0; kk < 2; ++kk) {
    const float4 f0 = *(const float4*)(feat + cr * 64 + kk * 32 + quad * 8);
    const float4 f1 = *(const float4*)(feat + cr * 64 + kk * 32 + quad * 8 + 4);
    Frag v;
    v.s[0] = (short)f2bf(f0.x); v.s[1] = (short)f2bf(f0.y);
    v.s[2] = (short)f2bf(f0.z); v.s[3] = (short)f2bf(f0.w);
    v.s[4] = (short)f2bf(f1.x); v.s[5] = (short)f2bf(f1.y);
    v.s[6] = (short)f2bf(f1.z); v.s[7] = (short)f2bf(f1.w);
    xf[kk] = v.s;
    if (act) *(uint4*)(featb + cr * 64 + kk * 32 + quad * 8) = v.u;
  }

  // Q = bottom half of [P|Q]: w1pq mt = 4..7
  short8 wf[4][2];
  #pragma unroll
  for (int m = 0; m < 4; ++m)
    #pragma unroll
    for (int kk = 0; kk < 2; ++kk)
      wf[m][kk] = *(const short8*)(w1pq + ((((m + 4) * 2 + kk) * 4 + quad) << 7) + l15 * 8);

  f32x4 acc[4] = {};
  #pragma unroll
  for (int kk = 0; kk < 2; ++kk)
    #pragma unroll
    for (int m = 0; m < 4; ++m)
      acc[m] = __builtin_amdgcn_mfma_f32_16x16x32_bf16(wf[m][kk], xf[kk], acc[m], 0, 0, 0);

  if (act) {
    #pragma unroll
    for (int m = 0; m < 4; ++m) {          // Q: fp8 e4m3 (HW cvt pair)
      int w = __builtin_amdgcn_cvt_pk_fp8_f32(acc[m][0], acc[m][1], 0, false);
      w = __builtin_amdgcn_cvt_pk_fp8_f32(acc[m][2], acc[m][3], w, true);
      *(unsigned int*)(Q8 + cr * 64 + m * 16 + quad * 4) = (unsigned)w;
    }
  }
}

// ------------------------------------------------------------ msg_tail ----
// One block per 16-cell tile (3125 blocks, 4 waves).
__global__ __launch_bounds__(256) void msg_tail_kernel(
    const unsigned short* __restrict__ featb,
    const unsigned char* __restrict__ Q8,
    const float4* __restrict__ cent4,
    const int* __restrict__ nbr,
    const float* __restrict__ feat,
    const unsigned short* __restrict__ w1pq,
    const unsigned short* __restrict__ w2t,
    const unsigned short* __restrict__ wu1t,
    const unsigned short* __restrict__ wu2b,
    const float* __restrict__ b1, const float* __restrict__ W1,
    const float* __restrict__ b2, const float* __restrict__ bu1,
    const float* __restrict__ bu2,
    float* __restrict__ outf)
{
  __shared__ uint4 smem[432];   // sT (P then s) 16x144B | Msg 16x144B | Hb 16x144B
  char* sT  = (char*)smem;
  char* Msg = sT + 2304;
  char* Hb  = sT + 4608;

  const int lane = threadIdx.x & 63;
  const int wid  = threadIdx.x >> 6;
  const int quad = lane >> 4;
  const int l15  = lane & 15;
  const int tile = blockIdx.x;
  const int cr   = tile * 16 + l15;

  // ---- phase 0: P-tile^T = W1top^T x X^T (mt = wid) -> LDS bf16 ----
  {
    short8 wpf[2];
    #pragma unroll
    for (int kk = 0; kk < 2; ++kk)
      wpf[kk] = *(const short8*)(w1pq + (((wid * 2 + kk) * 4 + quad) << 7) + l15 * 8);
    f32x4 accp = {};
    #pragma unroll
    for (int kk = 0; kk < 2; ++kk) {
      const short8 bf = *(const short8*)(featb + cr * 64 + kk * 32 + quad * 8);
      accp = __builtin_amdgcn_mfma_f32_16x16x32_bf16(wpf[kk], bf, accp, 0, 0, 0);
    }
    uint2 pk;
    pk.x = f2bf(accp[0]) | (f2bf(accp[1]) << 16);
    pk.y = f2bf(accp[2]) | (f2bf(accp[3]) << 16);
    *(uint2_a*)(sT + l15 * 144 + wid * 32 + quad * 8) = pk;
  }

  __syncthreads();

  // ---- phase A: gather 4 cells per wave; geom inline ----
  const float b1l = b1[lane];
  const float wl  = W1[8192 + lane];

  #pragma unroll
  for (int i = 0; i < 4; ++i) {
    const int c  = tile * 16 + wid * 4 + i;
    const int cs = __builtin_amdgcn_readfirstlane(c);
    const int* nrow = nbr + cs * DEG;

    // geom: lanes (lane&15)=d gather cent4[nbr[cs,d]]
    const int njl = nrow[lane & 15];
    const float4 ci = cent4[cs];           // uniform -> s_load
    const float4 cj = cent4[njl];          // random 16B gather
    const float dx = ci.x - cj.x, dy = ci.y - cj.y, dz = ci.z - cj.z;
    const float g = sqrtf(dx * dx + dy * dy + dz * dz);

    const float pcb =
        bf2f(((const ushort_a*)(sT + (wid * 4 + i) * 144))[lane]) + b1l;

    float acc = 0.f;
    #pragma unroll
    for (int d = 0; d < DEG; ++d) {
      const int   nd = nrow[d];            // uniform -> s_load
      const float gd = __uint_as_float(
          __builtin_amdgcn_readlane((int)__float_as_uint(g), d));
      const float qv = __builtin_amdgcn_cvt_f32_fp8((int)Q8[nd * 64 + lane], 0);
      acc += silu_fast(pcb + qv + gd * wl);
    }
    // overwrite own P row with s (only this wave reads this row's P)
    ((ushort_a*)(sT + (wid * 4 + i) * 144))[lane] =
        (unsigned short)f2bf(acc * 0.0625f);
  }

  // wave w's weight frags (mt/nt = wid only)
  short8 w2f[2], wu1f[4], wu2f[2];
  #pragma unroll
  for (int kk = 0; kk < 2; ++kk)
    w2f[kk]  = *(const short8*)(w2t  + (((wid * 2 + kk) * 4 + quad) << 7) + l15 * 8);
  #pragma unroll
  for (int kk = 0; kk < 4; ++kk)
    wu1f[kk] = *(const short8*)(wu1t + (((wid * 4 + kk) * 4 + quad) << 7) + l15 * 8);
  #pragma unroll
  for (int kk = 0; kk < 2; ++kk)
    wu2f[kk] = *(const short8*)(wu2b + (((wid * 2 + kk) * 4 + quad) << 7) + l15 * 8);

  const f32x4 b2f  = *(const f32x4*)(b2  + wid * 16 + quad * 4);
  const f32x4 bu1f = *(const f32x4*)(bu1 + wid * 16 + quad * 4);
  const float bu2v = bu2[wid * 16 + l15];

  __syncthreads();

  // ---- stage 1: msg^T = W2^T x s^T (+b2), mt = wid ----
  f32x4 accm = {};
  #pragma unroll
  for (int kk = 0; kk < 2; ++kk) {
    HbRd t; t.u = *(const uint4_a*)(sT + l15 * 144 + kk * 64 + quad * 16);
    accm = __builtin_amdgcn_mfma_f32_16x16x32_bf16(w2f[kk], t.s, accm, 0, 0, 0);
  }
  {
    uint2 pk;
    pk.x = f2bf(accm[0] + b2f[0]) | (f2bf(accm[1] + b2f[1]) << 16);
    pk.y = f2bf(accm[2] + b2f[2]) | (f2bf(accm[3] + b2f[3]) << 16);
    *(uint2_a*)(Msg + l15 * 144 + wid * 32 + quad * 8) = pk;
  }
  __syncthreads();

  // ---- stage 2: hu^T = Wu1^T x [feat|msg]^T (+bu1, silu), mt = wid ----
  f32x4 accu = {};
  #pragma unroll
  for (int kk = 0; kk < 4; ++kk) {
    short8 bf;
    if (kk < 2) {
      bf = *(const short8*)(featb + cr * 64 + kk * 32 + quad * 8);
    } else {
      HbRd t; t.u = *(const uint4_a*)(Msg + l15 * 144 + (kk - 2) * 64 + quad * 16);
      bf = t.s;
    }
    accu = __builtin_amdgcn_mfma_f32_16x16x32_bf16(wu1f[kk], bf, accu, 0, 0, 0);
  }
  {
    float sv[4];
    #pragma unroll
    for (int rg = 0; rg < 4; ++rg)
      sv[rg] = silu(accu[rg] + bu1f[rg]);
    uint2 pk;
    pk.x = f2bf(sv[0]) | (f2bf(sv[1]) << 16);
    pk.y = f2bf(sv[2]) | (f2bf(sv[3]) << 16);
    *(uint2_a*)(Hb + l15 * 144 + wid * 32 + quad * 8) = pk;
  }
  __syncthreads();

  // ---- stage 3: out = hu x Wu2 + bu2 + feat, nt = wid ----
  f32x4 acc2 = {};
  #pragma unroll
  for (int kk = 0; kk < 2; ++kk) {
    HbRd t; t.u = *(const uint4_a*)(Hb + l15 * 144 + kk * 64 + quad * 16);
    acc2 = __builtin_amdgcn_mfma_f32_16x16x32_bf16(t.s, wu2f[kk], acc2, 0, 0, 0);
  }
  #pragma unroll
  for (int rg = 0; rg < 4; ++rg) {
    const int row = tile * 16 + quad * 4 + rg;
    const int col = wid * 16 + l15;
    outf[row * 64 + col] = feat[row * 64 + col] + acc2[rg] + bu2v;
  }
}

// -------------------------------------------------------------- launch ----
extern "C" void kernel_launch(void* const* d_in, const int* in_sizes, int n_in,
                              void* d_out, int out_size, void* d_ws, size_t ws_size,
                              hipStream_t stream)
{
  const float* feat = (const float*)d_in[0];
  const float* pos  = (const float*)d_in[1];
  const int*   nbr  = (const int*)d_in[2];
  const float* W1   = (const float*)d_in[3];
  const float* b1   = (const float*)d_in[4];
  const float* W2   = (const float*)d_in[5];
  const float* b2   = (const float*)d_in[6];
  const float* Wu1  = (const float*)d_in[7];
  const float* bu1  = (const float*)d_in[8];
  const float* Wu2  = (const float*)d_in[9];
  const float* bu2  = (const float*)d_in[10];
  float* out = (float*)d_out;

  // ws: featb 6.4M @0 | Q8 fp8 3.2M @12.8M | cent4 0.8M @25.6M
  //   | swizzled weights @26.4M
  unsigned short* featb = (unsigned short*)d_ws;
  unsigned char*  Q8    = (unsigned char*)((char*)d_ws + 12800000);
  float*          cent4 = (float*)((char*)d_ws + 25600000);
  unsigned short* w1pq  = (unsigned short*)((char*)d_ws + 26400000);
  unsigned short* w2t   = (unsigned short*)((char*)d_ws + 26416384);
  unsigned short* wu1t  = (unsigned short*)((char*)d_ws + 26424576);
  unsigned short* wu2b  = (unsigned short*)((char*)d_ws + 26440960);

  aux_kernel<<<878, 256, 0, stream>>>(pos, W1, W2, Wu1, Wu2, out + 3200000,
                                      cent4, w1pq, w2t, wu1t, wu2b);
  prep_kernel<<<782, 256, 0, stream>>>(feat, w1pq, featb, Q8);
  msg_tail_kernel<<<3125, 256, 0, stream>>>(featb, Q8, (const float4*)cent4,
                                            nbr, feat, w1pq, w2t, wu1t, wu2b,
                                            b1, W1, b2, bu1, bu2, out);
}